// Round 13
// baseline (6255.636 us; speedup 1.0000x reference)
//
#include <hip/hip_runtime.h>

#define B_ 256
#define S_ 512
#define E_ 128
#define H_ 256
#define FH_ 1024
#define HROW 264  // 256 + 8 pad (shorts) -> row offset 132 dwords = 4 mod 32, conflict-free

typedef __bf16 bf16x8 __attribute__((ext_vector_type(8)));
typedef float f32x4 __attribute__((ext_vector_type(4)));
typedef unsigned short u16x4 __attribute__((ext_vector_type(4)));
typedef unsigned short u16x8 __attribute__((ext_vector_type(8)));
typedef unsigned long long u64_;

__device__ __forceinline__ unsigned short f2bf(float f) {
  union { float f; unsigned int u; } a; a.f = f;
  unsigned int u = a.u;
  u += 0x7fffu + ((u >> 16) & 1u);  // RNE
  return (unsigned short)(u >> 16);
}
__device__ __forceinline__ float bf2f(unsigned short v) {
  union { unsigned int u; float f; } a; a.u = ((unsigned int)v) << 16;
  return a.f;
}
__device__ __forceinline__ float sigm(float x) { return 1.f / (1.f + __expf(-x)); }
__device__ __forceinline__ float tanh_(float x) {
  float e = __expf(2.f * x);
  return 1.f - 2.f / (e + 1.f);
}

// ---------------- workspace layout (bytes) ----------------
#define OFF_ENC    ((size_t)0)          // enc_out bf16 [256][512][256]  67108864
#define OFF_WHHE   ((size_t)67108864)   // enc_Whh bf16 [1024][256]        524288
#define OFF_WHHP   ((size_t)67633152)   // pb_Whh  bf16                    524288
#define OFF_WREF   ((size_t)68157440)   // Wref    bf16 [256][256]         131072
#define OFF_MENC   ((size_t)68288512)   // M = enc_Wih@W_emb f32 [1024][2]   8192
#define OFF_BIASE  ((size_t)68296704)   // enc_bih+enc_bhh f32 [1024]        4096
#define OFF_XPV    ((size_t)68300800)   // pb x-projection f32 [1024]        4096
#define OFF_FLAGS  ((size_t)68304896)   // u32 flags [8 pairs][2 half][8 wave] 1024
#define OFF_HX     ((size_t)68305920)   // h exchange bf16 [2][32][128][16]  262144
#define OFF_HFIN   ((size_t)68568064)   // final h f32 [256][256]          262144
#define OFF_QBUF   ((size_t)68830208)   // q f32 [256][256]                262144
#define OFF_UBUF   ((size_t)69092352)   // u f32 [256][512]                524288

// ---------------- K0: prep (weight conversion, folded projections, zeroing) ----
__global__ void k0_prep(const float* __restrict__ eWih, const float* __restrict__ eWhh,
                        const float* __restrict__ ebih, const float* __restrict__ ebhh,
                        const float* __restrict__ pWih, const float* __restrict__ pWhh,
                        const float* __restrict__ pbih, const float* __restrict__ pbhh,
                        const float* __restrict__ W_emb, const float* __restrict__ dec_in,
                        const float* __restrict__ Wref,
                        unsigned short* __restrict__ WhhE, unsigned short* __restrict__ WhhP,
                        unsigned short* __restrict__ Wrefb,
                        float* __restrict__ Menc, float* __restrict__ biasE,
                        float* __restrict__ xpv,
                        unsigned int* __restrict__ flags, float* __restrict__ ubuf) {
  int gid = blockIdx.x * blockDim.x + threadIdx.x;
  int NT = gridDim.x * blockDim.x;
  for (int i = gid; i < FH_ * H_; i += NT) {
    WhhE[i] = f2bf(eWhh[i]);
    WhhP[i] = f2bf(pWhh[i]);
  }
  for (int i = gid; i < H_ * H_; i += NT) Wrefb[i] = f2bf(Wref[i]);
  for (int i = gid; i < B_ * S_; i += NT) ubuf[i] = 0.f;
  if (gid < 256) flags[gid] = 0u;
  if (gid < FH_) {
    int n = gid;
    float m0 = 0.f, m1 = 0.f, xs = 0.f;
    for (int e = 0; e < E_; ++e) {
      float w = eWih[n * E_ + e];
      m0 += w * W_emb[e * 2 + 0];
      m1 += w * W_emb[e * 2 + 1];
      xs += pWih[n * E_ + e] * dec_in[e];
    }
    Menc[n * 2 + 0] = m0;
    Menc[n * 2 + 1] = m1;
    biasE[n] = ebih[n] + ebhh[n];
    xpv[n] = xs + pbih[n] + pbhh[n];
  }
}

// ---------------- K1: persistent dual-LSTM, dual-group interleave -----------
// 16 WGs x 512 threads. Pair p (WGs p and p+8) owns batch groups 2p, 2p+1
// (32 rows) and splits the 1024 gate columns (half = blk>>3).
// Weights are batch-independent: the same 32 named fragments (asm-pinned,
// R8-proven) serve BOTH groups, so the per-step cross-WG exchange cost
// (drain + flag RTT + hx load RTT at the L3 coherence point, ~4400cy of
// R8's 7000cy step) is paid ONCE for two groups:
//   compute A (GEMM+gates) ; compute B ; one vmcnt(0) drain ; one per-wave
//   flag ; poll peer ; both hx loads issued together ; unpack ; one barrier.
// Protocol pieces all from PASSING kernels: R8 weight handling + gates,
// R10 per-wave flag (vmcnt(0)+lane0 store, monotonic targets), R5/R9
// double-buffered LDS h. h(0)=0 comes from LDS init (hx never read at t=0;
// first publish/poll value is 2; flags zeroed by k0).
__launch_bounds__(512)
__attribute__((amdgpu_waves_per_eu(2, 2)))
__global__ void k1_lstm(const float* __restrict__ inp,
                        const unsigned short* __restrict__ WhhE,
                        const unsigned short* __restrict__ WhhP,
                        const float* __restrict__ Menc, const float* __restrict__ biasE,
                        const float* __restrict__ xpv,
                        unsigned short* __restrict__ enc_out,
                        unsigned short* __restrict__ hx,
                        unsigned int* __restrict__ flags,
                        float* __restrict__ hfin) {
  __shared__ unsigned short hbA[2][16 * HROW];  // group A h, double-buffered
  __shared__ unsigned short hbB[2][16 * HROW];  // group B h
  __shared__ float xinA[2][16][2], xinB[2][16][2];
  const int tid = threadIdx.x;
  const int wave = tid >> 6, lane = tid & 63, quad = lane >> 4, l16 = lane & 15;
  const int blk = blockIdx.x;
  const int p = blk & 7;           // pair 0..7
  const int half = blk >> 3;       // 0..1 column half
  const int gA = p * 2, gB = p * 2 + 1;
  const int kloc = (wave << 4) | l16;    // 0..127 within half
  const int kcol = half * 128 + kloc;    // 0..255 global h-column

  for (int i = tid; i < 16 * HROW; i += 512) {
    hbA[0][i] = 0; hbB[0][i] = 0;
  }
  if (tid < 64) {
    int g_ = tid >> 5, tt = tid & 31;
    int grp = g_ ? gB : gA;
    float v = inp[((grp * 16 + (tt >> 1)) * S_ + 0) * 2 + (tt & 1)];
    if (g_) xinB[0][tt >> 1][tt & 1] = v; else xinA[0][tt >> 1][tt & 1] = v;
  }

  float cA[4] = {0.f, 0.f, 0.f, 0.f}, cB[4] = {0.f, 0.f, 0.f, 0.f};
  float hrA[4] = {0.f, 0.f, 0.f, 0.f}, hrB[4] = {0.f, 0.f, 0.f, 0.f};
  // 32 named weight fragments (4 gates x 8 k-chunks), 128 VGPRs target.
  f32x4 W00, W01, W02, W03, W04, W05, W06, W07;
  f32x4 W10, W11, W12, W13, W14, W15, W16, W17;
  f32x4 W20, W21, W22, W23, W24, W25, W26, W27;
  f32x4 W30, W31, W32, W33, W34, W35, W36, W37;
  float m0c[4], m1c[4], bc[4];
  unsigned int* myflag = flags + ((p * 2 + half) << 3) + wave;
  unsigned int* pflag = flags + ((p * 2 + (1 - half)) << 3) + wave;
  const f32x4 z4 = {0.f, 0.f, 0.f, 0.f};
  __syncthreads();

  int t = 0;
#pragma unroll 1
  for (int phase = 0; phase < 2; ++phase) {
    const unsigned short* W = phase ? WhhP : WhhE;
#define WLOAD(g)                                                        \
    {                                                                   \
      const unsigned short* wp = W + ((g) * 256 + kcol) * H_ + quad * 8; \
      W##g##0 = *(const f32x4*)(wp + 0 * 32);                           \
      W##g##1 = *(const f32x4*)(wp + 1 * 32);                           \
      W##g##2 = *(const f32x4*)(wp + 2 * 32);                           \
      W##g##3 = *(const f32x4*)(wp + 3 * 32);                           \
      W##g##4 = *(const f32x4*)(wp + 4 * 32);                           \
      W##g##5 = *(const f32x4*)(wp + 5 * 32);                           \
      W##g##6 = *(const f32x4*)(wp + 6 * 32);                           \
      W##g##7 = *(const f32x4*)(wp + 7 * 32);                           \
    }
    WLOAD(0) WLOAD(1) WLOAD(2) WLOAD(3)
#undef WLOAD
    asm volatile(""
                 : "+v"(W00), "+v"(W01), "+v"(W02), "+v"(W03),
                   "+v"(W04), "+v"(W05), "+v"(W06), "+v"(W07),
                   "+v"(W10), "+v"(W11), "+v"(W12), "+v"(W13),
                   "+v"(W14), "+v"(W15), "+v"(W16), "+v"(W17),
                   "+v"(W20), "+v"(W21), "+v"(W22), "+v"(W23),
                   "+v"(W24), "+v"(W25), "+v"(W26), "+v"(W27),
                   "+v"(W30), "+v"(W31), "+v"(W32), "+v"(W33),
                   "+v"(W34), "+v"(W35), "+v"(W36), "+v"(W37));
#pragma unroll
    for (int gg = 0; gg < 4; ++gg) {
      int n = gg * 256 + kcol;
      if (phase == 0) {
        m0c[gg] = Menc[n * 2 + 0]; m1c[gg] = Menc[n * 2 + 1]; bc[gg] = biasE[n];
      } else {
        m0c[gg] = 0.f; m1c[gg] = 0.f; bc[gg] = xpv[n];
      }
    }

#define MS(kt, HB)                                                             \
    {                                                                          \
      bf16x8 Af = *(const bf16x8*)((HB) + l16 * HROW + kt * 32 + quad * 8);    \
      acc0 = __builtin_amdgcn_mfma_f32_16x16x32_bf16(                          \
          Af, __builtin_bit_cast(bf16x8, W0##kt), acc0, 0, 0, 0);              \
      acc1 = __builtin_amdgcn_mfma_f32_16x16x32_bf16(                          \
          Af, __builtin_bit_cast(bf16x8, W1##kt), acc1, 0, 0, 0);              \
      acc2 = __builtin_amdgcn_mfma_f32_16x16x32_bf16(                          \
          Af, __builtin_bit_cast(bf16x8, W2##kt), acc2, 0, 0, 0);              \
      acc3 = __builtin_amdgcn_mfma_f32_16x16x32_bf16(                          \
          Af, __builtin_bit_cast(bf16x8, W3##kt), acc3, 0, 0, 0);              \
    }
#define GEMM8(HB) MS(0, HB) MS(1, HB) MS(2, HB) MS(3, HB) \
                  MS(4, HB) MS(5, HB) MS(6, HB) MS(7, HB)

#pragma unroll 1
    for (int step = 0; step < 512; ++step, ++t) {
      const int cur = t & 1, nxt = cur ^ 1;
      // ---- prefetch next x for both groups ----
      float xpre = 0.f;
      if (phase == 0 && tid < 64) {
        int g_ = tid >> 5, tt = tid & 31;
        int grp = g_ ? gB : gA;
        int sN = (step < 511) ? step + 1 : 511;
        xpre = inp[((grp * 16 + (tt >> 1)) * S_ + sN) * 2 + (tt & 1)];
      }
      unsigned short hb4A[4], hb4B[4];
      // ================= group A =================
      {
        f32x4 acc0 = z4, acc1 = z4, acc2 = z4, acc3 = z4;
        GEMM8(&hbA[cur][0])
#pragma unroll
        for (int r = 0; r < 4; ++r) {
          int bl = quad * 4 + r;
          float x0 = xinA[cur][bl][0], x1 = xinA[cur][bl][1];
          float gi = acc0[r] + x0 * m0c[0] + x1 * m1c[0] + bc[0];
          float gf = acc1[r] + x0 * m0c[1] + x1 * m1c[1] + bc[1];
          float gc = acc2[r] + x0 * m0c[2] + x1 * m1c[2] + bc[2];
          float go = acc3[r] + x0 * m0c[3] + x1 * m1c[3] + bc[3];
          float cn = sigm(gf) * cA[r] + sigm(gi) * tanh_(gc);
          cA[r] = cn;
          hrA[r] = sigm(go) * tanh_(cn);
          hb4A[r] = f2bf(hrA[r]);
        }
        if (phase == 0) {
#pragma unroll
          for (int r = 0; r < 4; ++r)
            enc_out[(((size_t)(gA * 16 + quad * 4 + r) * S_ + step)) * H_ + kcol] = hb4A[r];
        }
        unsigned short* hxs = hx + ((size_t)(nxt * 32 + gA * 2 + half)) * 2048;
        u64_ pack = (u64_)hb4A[0] | ((u64_)hb4A[1] << 16) | ((u64_)hb4A[2] << 32) |
                    ((u64_)hb4A[3] << 48);
        __hip_atomic_store((u64_*)(hxs + kloc * 16 + quad * 4), pack,
                           __ATOMIC_RELAXED, __HIP_MEMORY_SCOPE_AGENT);
#pragma unroll
        for (int r = 0; r < 4; ++r) hbA[nxt][(quad * 4 + r) * HROW + kcol] = hb4A[r];
      }
      // ================= group B =================
      {
        f32x4 acc0 = z4, acc1 = z4, acc2 = z4, acc3 = z4;
        GEMM8(&hbB[cur][0])
#pragma unroll
        for (int r = 0; r < 4; ++r) {
          int bl = quad * 4 + r;
          float x0 = xinB[cur][bl][0], x1 = xinB[cur][bl][1];
          float gi = acc0[r] + x0 * m0c[0] + x1 * m1c[0] + bc[0];
          float gf = acc1[r] + x0 * m0c[1] + x1 * m1c[1] + bc[1];
          float gc = acc2[r] + x0 * m0c[2] + x1 * m1c[2] + bc[2];
          float go = acc3[r] + x0 * m0c[3] + x1 * m1c[3] + bc[3];
          float cn = sigm(gf) * cB[r] + sigm(gi) * tanh_(gc);
          cB[r] = cn;
          hrB[r] = sigm(go) * tanh_(cn);
          hb4B[r] = f2bf(hrB[r]);
        }
        if (phase == 0) {
#pragma unroll
          for (int r = 0; r < 4; ++r)
            enc_out[(((size_t)(gB * 16 + quad * 4 + r) * S_ + step)) * H_ + kcol] = hb4B[r];
        }
        unsigned short* hxs = hx + ((size_t)(nxt * 32 + gB * 2 + half)) * 2048;
        u64_ pack = (u64_)hb4B[0] | ((u64_)hb4B[1] << 16) | ((u64_)hb4B[2] << 32) |
                    ((u64_)hb4B[3] << 48);
        __hip_atomic_store((u64_*)(hxs + kloc * 16 + quad * 4), pack,
                           __ATOMIC_RELAXED, __HIP_MEMORY_SCOPE_AGENT);
#pragma unroll
        for (int r = 0; r < 4; ++r) hbB[nxt][(quad * 4 + r) * HROW + kcol] = hb4B[r];
      }
      // ---- one drain, one per-wave flag covering both groups ----
      asm volatile("s_waitcnt vmcnt(0)" ::: "memory");
      if (lane == 0)
        __hip_atomic_store(myflag, (unsigned int)(t + 2), __ATOMIC_RELAXED,
                           __HIP_MEMORY_SCOPE_AGENT);
      if (phase == 0 && tid < 64) {
        int g_ = tid >> 5, tt = tid & 31;
        if (g_) xinB[nxt][tt >> 1][tt & 1] = xpre;
        else xinA[nxt][tt >> 1][tt & 1] = xpre;
      }
      // ---- poll peer (wave-uniform), then both hx loads together ----
      {
        const unsigned int target = (unsigned int)(t + 2);
        while (__hip_atomic_load(pflag, __ATOMIC_RELAXED, __HIP_MEMORY_SCOPE_AGENT) <
               target) {
          __builtin_amdgcn_s_sleep(1);
        }
        const unsigned short* phA =
            hx + ((size_t)(nxt * 32 + gA * 2 + (1 - half))) * 2048;
        const unsigned short* phB =
            hx + ((size_t)(nxt * 32 + gB * 2 + (1 - half))) * 2048;
        u64_ pvA = __hip_atomic_load((const u64_*)(phA + tid * 4), __ATOMIC_RELAXED,
                                     __HIP_MEMORY_SCOPE_AGENT);
        u64_ pvB = __hip_atomic_load((const u64_*)(phB + tid * 4), __ATOMIC_RELAXED,
                                     __HIP_MEMORY_SCOPE_AGENT);
        int kp = tid >> 2, r0 = (tid & 3) * 4;
        unsigned short* dA = &hbA[nxt][0] + (1 - half) * 128 + kp;
        dA[(size_t)(r0 + 0) * HROW] = (unsigned short)(pvA);
        dA[(size_t)(r0 + 1) * HROW] = (unsigned short)(pvA >> 16);
        dA[(size_t)(r0 + 2) * HROW] = (unsigned short)(pvA >> 32);
        dA[(size_t)(r0 + 3) * HROW] = (unsigned short)(pvA >> 48);
        unsigned short* dB = &hbB[nxt][0] + (1 - half) * 128 + kp;
        dB[(size_t)(r0 + 0) * HROW] = (unsigned short)(pvB);
        dB[(size_t)(r0 + 1) * HROW] = (unsigned short)(pvB >> 16);
        dB[(size_t)(r0 + 2) * HROW] = (unsigned short)(pvB >> 32);
        dB[(size_t)(r0 + 3) * HROW] = (unsigned short)(pvB >> 48);
      }
      __syncthreads();  // hbA/hbB[nxt] + xin[nxt] ready for next step
    }
#undef GEMM8
#undef MS
  }
  // final h (fp32) for the attention query
#pragma unroll
  for (int r = 0; r < 4; ++r) {
    hfin[(gA * 16 + quad * 4 + r) * H_ + kcol] = hrA[r];
    hfin[(gB * 16 + quad * 4 + r) * H_ + kcol] = hrB[r];
  }
}

// ---------------- K1b: q = h @ Wq^T + bq (fp32) ----------------
__global__ void k1b_q(const float* __restrict__ hfin, const float* __restrict__ Wq,
                      const float* __restrict__ bq, float* __restrict__ qbuf) {
  __shared__ float hl[H_];
  int b = blockIdx.x, j = threadIdx.x;
  hl[j] = hfin[b * H_ + j];
  __syncthreads();
  float s = bq[j];
  const float* w = Wq + j * H_;
  for (int k = 0; k < H_; ++k) s += hl[k] * w[k];
  qbuf[b * H_ + j] = s;
}

// ---------------- K2: u = tanh(enc_out@Wref^T + bref + q) @ V (fused) ----------
__launch_bounds__(512)
__global__ void k2_att(const unsigned short* __restrict__ enc_out,
                       const unsigned short* __restrict__ Wrefb,
                       const float* __restrict__ qbuf, const float* __restrict__ bref,
                       const float* __restrict__ V, float* __restrict__ ubuf) {
  __shared__ unsigned short Bs[128 * HROW];
  __shared__ float qs[128], Vs[128];
  int tid = threadIdx.x;
  int wave = tid >> 6, lane = tid & 63, quad = lane >> 4, l16 = lane & 15;
  int rowblk = blockIdx.x >> 1, nb = blockIdx.x & 1;
  int b = rowblk >> 2;
  {  // stage Wref block [nb*128 .. +128) x 256 into LDS
    int nl = tid >> 2, seg = tid & 3;
    const unsigned short* src = Wrefb + (nb * 128 + nl) * H_ + seg * 64;
    unsigned short* dst = Bs + nl * HROW + seg * 64;
#pragma unroll
    for (int i = 0; i < 8; ++i) *(u16x8*)(dst + i * 8) = *(const u16x8*)(src + i * 8);
  }
  if (tid < 128) {
    int j = nb * 128 + tid;
    qs[tid] = qbuf[b * H_ + j] + bref[j];
    Vs[tid] = V[j];
  }
  __syncthreads();
  int rw = rowblk * 128 + wave * 16 + l16;  // global (b,s) row
  const f32x4 z4 = {0.f, 0.f, 0.f, 0.f};
  f32x4 acc[8];
#pragma unroll
  for (int kt = 0; kt < 8; ++kt) {
    bf16x8 af = *(const bf16x8*)(enc_out + (size_t)rw * H_ + kt * 32 + quad * 8);
#pragma unroll
    for (int nt = 0; nt < 8; ++nt) {
      bf16x8 bfr = *(const bf16x8*)(Bs + (nt * 16 + l16) * HROW + kt * 32 + quad * 8);
      acc[nt] = __builtin_amdgcn_mfma_f32_16x16x32_bf16(af, bfr, (kt == 0) ? z4 : acc[nt],
                                                        0, 0, 0);
    }
  }
  float part[4] = {0.f, 0.f, 0.f, 0.f};
#pragma unroll
  for (int nt = 0; nt < 8; ++nt) {
    float qv = qs[nt * 16 + l16], vv = Vs[nt * 16 + l16];
#pragma unroll
    for (int r = 0; r < 4; ++r) part[r] += tanh_(acc[nt][r] + qv) * vv;
  }
#pragma unroll
  for (int m = 1; m < 16; m <<= 1) {
#pragma unroll
    for (int r = 0; r < 4; ++r) part[r] += __shfl_xor(part[r], m, 64);
  }
  if (l16 == 0) {
    int s0 = (rowblk & 3) * 128 + wave * 16 + quad * 4;
#pragma unroll
    for (int r = 0; r < 4; ++r) atomicAdd(&ubuf[b * S_ + s0 + r], part[r]);
  }
}

// ---------------- K3: softmax + glimpse + decoder head ----------------
__global__ void k3_head(const float* __restrict__ ubuf,
                        const unsigned short* __restrict__ enc_out,
                        const float* __restrict__ Wd1, const float* __restrict__ Wd2,
                        float* __restrict__ out) {
  __shared__ float sm[512];
  __shared__ float red[256];
  __shared__ float gl[256];
  int b = blockIdx.x, tid = threadIdx.x;
  float u0 = ubuf[b * S_ + tid], u1 = ubuf[b * S_ + 256 + tid];
  red[tid] = fmaxf(u0, u1);
  __syncthreads();
  for (int s = 128; s > 0; s >>= 1) {
    if (tid < s) red[tid] = fmaxf(red[tid], red[tid + s]);
    __syncthreads();
  }
  float mx = red[0];
  __syncthreads();
  float e0 = __expf(u0 - mx), e1 = __expf(u1 - mx);
  red[tid] = e0 + e1;
  __syncthreads();
  for (int s = 128; s > 0; s >>= 1) {
    if (tid < s) red[tid] += red[tid + s];
    __syncthreads();
  }
  float inv = 1.f / red[0];
  sm[tid] = e0 * inv;
  sm[256 + tid] = e1 * inv;
  __syncthreads();
  float g = 0.f;
  const unsigned short* eo = enc_out + (size_t)b * S_ * H_ + tid;
  for (int s = 0; s < S_; ++s) g += sm[s] * bf2f(eo[(size_t)s * H_]);
  gl[tid] = g;
  __syncthreads();
  float y = 0.f;
  const float* w = Wd1 + tid * H_;
  for (int j = 0; j < H_; ++j) y += w[j] * gl[j];
  y = fmaxf(y, 0.f) * Wd2[tid];
  red[tid] = y;
  __syncthreads();
  for (int s = 128; s > 0; s >>= 1) {
    if (tid < s) red[tid] += red[tid + s];
    __syncthreads();
  }
  if (tid == 0) out[b] = red[0];
}

extern "C" void kernel_launch(void* const* d_in, const int* in_sizes, int n_in,
                              void* d_out, int out_size, void* d_ws, size_t ws_size,
                              hipStream_t stream) {
  (void)in_sizes; (void)n_in; (void)out_size; (void)ws_size;
  const float* inp    = (const float*)d_in[0];
  const float* W_emb  = (const float*)d_in[1];
  const float* dec_in = (const float*)d_in[2];
  const float* eWih   = (const float*)d_in[3];
  const float* eWhh   = (const float*)d_in[4];
  const float* ebih   = (const float*)d_in[5];
  const float* ebhh   = (const float*)d_in[6];
  const float* pWih   = (const float*)d_in[7];
  const float* pWhh   = (const float*)d_in[8];
  const float* pbih   = (const float*)d_in[9];
  const float* pbhh   = (const float*)d_in[10];
  const float* Wq     = (const float*)d_in[11];
  const float* bq     = (const float*)d_in[12];
  const float* Wref   = (const float*)d_in[13];
  const float* bref   = (const float*)d_in[14];
  const float* V      = (const float*)d_in[15];
  const float* Wd1    = (const float*)d_in[16];
  const float* Wd2    = (const float*)d_in[17];
  float* out = (float*)d_out;

  char* ws = (char*)d_ws;
  unsigned short* enc_out = (unsigned short*)(ws + OFF_ENC);
  unsigned short* WhhE    = (unsigned short*)(ws + OFF_WHHE);
  unsigned short* WhhP    = (unsigned short*)(ws + OFF_WHHP);
  unsigned short* Wrefb   = (unsigned short*)(ws + OFF_WREF);
  float* Menc  = (float*)(ws + OFF_MENC);
  float* biasE = (float*)(ws + OFF_BIASE);
  float* xpv   = (float*)(ws + OFF_XPV);
  unsigned int* flags = (unsigned int*)(ws + OFF_FLAGS);
  unsigned short* hx  = (unsigned short*)(ws + OFF_HX);
  float* hfin = (float*)(ws + OFF_HFIN);
  float* qbuf = (float*)(ws + OFF_QBUF);
  float* ubuf = (float*)(ws + OFF_UBUF);

  hipLaunchKernelGGL(k0_prep, dim3(256), dim3(256), 0, stream,
                     eWih, eWhh, ebih, ebhh, pWih, pWhh, pbih, pbhh, W_emb, dec_in,
                     Wref, WhhE, WhhP, Wrefb, Menc, biasE, xpv, flags, ubuf);
  hipLaunchKernelGGL(k1_lstm, dim3(16), dim3(512), 0, stream,
                     inp, WhhE, WhhP, Menc, biasE, xpv, enc_out, hx, flags, hfin);
  hipLaunchKernelGGL(k1b_q, dim3(256), dim3(256), 0, stream, hfin, Wq, bq, qbuf);
  hipLaunchKernelGGL(k2_att, dim3(2048), dim3(512), 0, stream,
                     enc_out, Wrefb, qbuf, bref, V, ubuf);
  hipLaunchKernelGGL(k3_head, dim3(256), dim3(256), 0, stream,
                     ubuf, enc_out, Wd1, Wd2, out);
}

// Round 14
// 2640.586 us; speedup vs baseline: 2.3690x; 2.3690x over previous
//
#include <hip/hip_runtime.h>

#define B_ 256
#define S_ 512
#define E_ 128
#define H_ 256
#define FH_ 1024
#define HROW 264  // 256 + 8 pad (shorts) -> row offset 132 dwords = 4 mod 32, conflict-free

typedef __bf16 bf16x8 __attribute__((ext_vector_type(8)));
typedef float f32x4 __attribute__((ext_vector_type(4)));
typedef unsigned short u16x4 __attribute__((ext_vector_type(4)));
typedef unsigned short u16x8 __attribute__((ext_vector_type(8)));
typedef unsigned long long u64_;

__device__ __forceinline__ unsigned short f2bf(float f) {
  union { float f; unsigned int u; } a; a.f = f;
  unsigned int u = a.u;
  u += 0x7fffu + ((u >> 16) & 1u);  // RNE
  return (unsigned short)(u >> 16);
}
__device__ __forceinline__ float bf2f(unsigned short v) {
  union { unsigned int u; float f; } a; a.u = ((unsigned int)v) << 16;
  return a.f;
}
// Approximation-rate reciprocal (v_rcp_f32, ~1ulp). Without -ffast-math the
// compiler emits a 10-instruction IEEE div sequence for 1.f/x -- the gates do
// 20 divisions/thread/step, which made the recurrence VALU-bound (R8 PMC:
// ~50% VALUBusy on active CUs). bf16 output swallows the rcp error.
__device__ __forceinline__ float rcp_(float x) {
  float r;
  asm("v_rcp_f32 %0, %1" : "=v"(r) : "v"(x));
  return r;
}
__device__ __forceinline__ float sigm(float x) { return rcp_(1.f + __expf(-x)); }
__device__ __forceinline__ float tanh_(float x) {
  return 1.f - 2.f * rcp_(__expf(2.f * x) + 1.f);
}
// One-instruction packed f32->bf16 (RNE), replaces two f2bf + shifts.
__device__ __forceinline__ unsigned int cvt_pk_bf16(float lo, float hi) {
  unsigned int r;
  asm("v_cvt_pk_bf16_f32 %0, %1, %2" : "=v"(r) : "v"(lo), "v"(hi));
  return r;
}

// ---------------- workspace layout (bytes) ----------------
#define OFF_ENC    ((size_t)0)          // enc_out bf16 [256][512][256]  67108864
#define OFF_WHHE   ((size_t)67108864)   // enc_Whh bf16 [1024][256]        524288
#define OFF_WHHP   ((size_t)67633152)   // pb_Whh  bf16                    524288
#define OFF_WREF   ((size_t)68157440)   // Wref    bf16 [256][256]         131072
#define OFF_MENC   ((size_t)68288512)   // M = enc_Wih@W_emb f32 [1024][2]   8192
#define OFF_BIASE  ((size_t)68296704)   // enc_bih+enc_bhh f32 [1024]        4096
#define OFF_XPV    ((size_t)68300800)   // pb x-projection f32 [1024]        4096
#define OFF_FLAGS  ((size_t)68304896)   // u32 flags                         1024
#define OFF_HX     ((size_t)68305920)   // h exchange bf16 [2][16][2][128][16] 262144
#define OFF_HFIN   ((size_t)68568064)   // final h f32 [256][256]          262144
#define OFF_QBUF   ((size_t)68830208)   // q f32 [256][256]                262144
#define OFF_UBUF   ((size_t)69092352)   // u f32 [256][512]                524288

// ---------------- K0: prep (weight conversion, folded projections, zeroing) ----
__global__ void k0_prep(const float* __restrict__ eWih, const float* __restrict__ eWhh,
                        const float* __restrict__ ebih, const float* __restrict__ ebhh,
                        const float* __restrict__ pWih, const float* __restrict__ pWhh,
                        const float* __restrict__ pbih, const float* __restrict__ pbhh,
                        const float* __restrict__ W_emb, const float* __restrict__ dec_in,
                        const float* __restrict__ Wref,
                        unsigned short* __restrict__ WhhE, unsigned short* __restrict__ WhhP,
                        unsigned short* __restrict__ Wrefb,
                        float* __restrict__ Menc, float* __restrict__ biasE,
                        float* __restrict__ xpv,
                        unsigned int* __restrict__ flags, float* __restrict__ ubuf) {
  int gid = blockIdx.x * blockDim.x + threadIdx.x;
  int NT = gridDim.x * blockDim.x;
  for (int i = gid; i < FH_ * H_; i += NT) {
    WhhE[i] = f2bf(eWhh[i]);
    WhhP[i] = f2bf(pWhh[i]);
  }
  for (int i = gid; i < H_ * H_; i += NT) Wrefb[i] = f2bf(Wref[i]);
  for (int i = gid; i < B_ * S_; i += NT) ubuf[i] = 0.f;
  if (gid < 256) flags[gid] = 0u;
  if (gid < FH_) {
    int n = gid;
    float m0 = 0.f, m1 = 0.f, xs = 0.f;
    for (int e = 0; e < E_; ++e) {
      float w = eWih[n * E_ + e];
      m0 += w * W_emb[e * 2 + 0];
      m1 += w * W_emb[e * 2 + 1];
      xs += pWih[n * E_ + e] * dec_in[e];
    }
    Menc[n * 2 + 0] = m0;
    Menc[n * 2 + 1] = m1;
    biasE[n] = ebih[n] + ebhh[n];
    xpv[n] = xs + pbih[n] + pbhh[n];
  }
}

// ---------------- K1: persistent dual-LSTM recurrence (R8 base) -------------
// 32 WGs x 512 threads; pair of WGs (halves) split the 1024 gate columns;
// 32 named weight fragments + asm pin (R8-proven). Exchange: R8's relaxed
// agent-atomic protocol, byte-identical (best measured: k1 3.08ms).
// This round changes ONLY the gate arithmetic (rcp-based sigm/tanh +
// v_cvt_pk_bf16_f32) -- R13 proved time scales with per-WG compute, and R8's
// per-active-CU VALUBusy ~50% shows the gates' 20 IEEE divisions/thread/step
// are on the critical path.
__launch_bounds__(512)
__attribute__((amdgpu_waves_per_eu(2, 2)))
__global__ void k1_lstm(const float* __restrict__ inp,
                        const unsigned short* __restrict__ WhhE,
                        const unsigned short* __restrict__ WhhP,
                        const float* __restrict__ Menc, const float* __restrict__ biasE,
                        const float* __restrict__ xpv,
                        unsigned short* __restrict__ enc_out,
                        unsigned short* __restrict__ hx,
                        unsigned int* __restrict__ flags,
                        float* __restrict__ hfin) {
  __shared__ unsigned short hbuf[16 * HROW];  // h bf16, 16 rows x (256+pad)
  __shared__ float xin[16][2];
  const int tid = threadIdx.x;
  const int wave = tid >> 6, lane = tid & 63, quad = lane >> 4, l16 = lane & 15;
  const int blk = blockIdx.x;
  const int grp = (blk & 7) | ((blk >> 4) << 3);  // 0..15
  const int half = (blk >> 3) & 1;
  const int kloc = (wave << 4) | l16;    // 0..127 within half
  const int kcol = half * 128 + kloc;    // 0..255 global h-column

  for (int i = tid; i < 16 * HROW; i += 512) hbuf[i] = 0;
  if (tid < 32) xin[tid >> 1][tid & 1] = inp[((grp * 16 + (tid >> 1)) * S_ + 0) * 2 + (tid & 1)];

  float c[4] = {0.f, 0.f, 0.f, 0.f};
  float hreg[4] = {0.f, 0.f, 0.f, 0.f};
  // 32 named weight fragments (4 gates x 8 k-chunks), 128 VGPRs target.
  f32x4 W00, W01, W02, W03, W04, W05, W06, W07;
  f32x4 W10, W11, W12, W13, W14, W15, W16, W17;
  f32x4 W20, W21, W22, W23, W24, W25, W26, W27;
  f32x4 W30, W31, W32, W33, W34, W35, W36, W37;
  float m0c[4], m1c[4], bc[4];
  unsigned int* myflag = flags + grp * 2 + half;
  unsigned int* pflag = flags + grp * 2 + (1 - half);
  const f32x4 z4 = {0.f, 0.f, 0.f, 0.f};
  __syncthreads();

  int t = 0;
#pragma unroll 1
  for (int phase = 0; phase < 2; ++phase) {
    const unsigned short* W = phase ? WhhP : WhhE;
#define WLOAD(g)                                                        \
    {                                                                   \
      const unsigned short* wp = W + ((g) * 256 + kcol) * H_ + quad * 8; \
      W##g##0 = *(const f32x4*)(wp + 0 * 32);                           \
      W##g##1 = *(const f32x4*)(wp + 1 * 32);                           \
      W##g##2 = *(const f32x4*)(wp + 2 * 32);                           \
      W##g##3 = *(const f32x4*)(wp + 3 * 32);                           \
      W##g##4 = *(const f32x4*)(wp + 4 * 32);                           \
      W##g##5 = *(const f32x4*)(wp + 5 * 32);                           \
      W##g##6 = *(const f32x4*)(wp + 6 * 32);                           \
      W##g##7 = *(const f32x4*)(wp + 7 * 32);                           \
    }
    WLOAD(0) WLOAD(1) WLOAD(2) WLOAD(3)
#undef WLOAD
    asm volatile(""
                 : "+v"(W00), "+v"(W01), "+v"(W02), "+v"(W03),
                   "+v"(W04), "+v"(W05), "+v"(W06), "+v"(W07),
                   "+v"(W10), "+v"(W11), "+v"(W12), "+v"(W13),
                   "+v"(W14), "+v"(W15), "+v"(W16), "+v"(W17),
                   "+v"(W20), "+v"(W21), "+v"(W22), "+v"(W23),
                   "+v"(W24), "+v"(W25), "+v"(W26), "+v"(W27),
                   "+v"(W30), "+v"(W31), "+v"(W32), "+v"(W33),
                   "+v"(W34), "+v"(W35), "+v"(W36), "+v"(W37));
#pragma unroll
    for (int gg = 0; gg < 4; ++gg) {
      int n = gg * 256 + kcol;
      if (phase == 0) {
        m0c[gg] = Menc[n * 2 + 0]; m1c[gg] = Menc[n * 2 + 1]; bc[gg] = biasE[n];
      } else {
        m0c[gg] = 0.f; m1c[gg] = 0.f; bc[gg] = xpv[n];
      }
    }
#pragma unroll 1
    for (int step = 0; step < 512; ++step, ++t) {
      // ---- prefetch next step's x (latency hidden under GEMM) ----
      float xpre = 0.f;
      if (phase == 0 && tid < 32) {
        int sN = (step < 511) ? step + 1 : 511;
        xpre = inp[((grp * 16 + (tid >> 1)) * S_ + sN) * 2 + (tid & 1)];
      }
      // ---- GEMM: g = h @ Whh^T (this WG's 512 columns) ----
      f32x4 acc0 = z4, acc1 = z4, acc2 = z4, acc3 = z4;
#define MSTEP(kt)                                                              \
      {                                                                        \
        bf16x8 Af = *(const bf16x8*)(hbuf + l16 * HROW + kt * 32 + quad * 8);  \
        acc0 = __builtin_amdgcn_mfma_f32_16x16x32_bf16(                        \
            Af, __builtin_bit_cast(bf16x8, W0##kt), acc0, 0, 0, 0);            \
        acc1 = __builtin_amdgcn_mfma_f32_16x16x32_bf16(                        \
            Af, __builtin_bit_cast(bf16x8, W1##kt), acc1, 0, 0, 0);            \
        acc2 = __builtin_amdgcn_mfma_f32_16x16x32_bf16(                        \
            Af, __builtin_bit_cast(bf16x8, W2##kt), acc2, 0, 0, 0);            \
        acc3 = __builtin_amdgcn_mfma_f32_16x16x32_bf16(                        \
            Af, __builtin_bit_cast(bf16x8, W3##kt), acc3, 0, 0, 0);            \
      }
      MSTEP(0) MSTEP(1) MSTEP(2) MSTEP(3) MSTEP(4) MSTEP(5) MSTEP(6) MSTEP(7)
#undef MSTEP
      // ---- gates (fp32, approximation-rate math). lane: rows quad*4+r, col kcol ----
      float hv[4];
#pragma unroll
      for (int r = 0; r < 4; ++r) {
        int bl = quad * 4 + r;
        float x0 = xin[bl][0], x1 = xin[bl][1];
        float gi = acc0[r] + x0 * m0c[0] + x1 * m1c[0] + bc[0];
        float gf = acc1[r] + x0 * m0c[1] + x1 * m1c[1] + bc[1];
        float gc = acc2[r] + x0 * m0c[2] + x1 * m1c[2] + bc[2];
        float go = acc3[r] + x0 * m0c[3] + x1 * m1c[3] + bc[3];
        float cn = sigm(gf) * c[r] + sigm(gi) * tanh_(gc);
        c[r] = cn;
        hv[r] = sigm(go) * tanh_(cn);
        hreg[r] = hv[r];
      }
      unsigned int pkA = cvt_pk_bf16(hv[0], hv[1]);  // hb0 | hb1<<16
      unsigned int pkB = cvt_pk_bf16(hv[2], hv[3]);  // hb2 | hb3<<16
      unsigned short hb[4];
      hb[0] = (unsigned short)pkA; hb[1] = (unsigned short)(pkA >> 16);
      hb[2] = (unsigned short)pkB; hb[3] = (unsigned short)(pkB >> 16);
      // ---- publish own half ----
      if (phase == 0) {
#pragma unroll
        for (int r = 0; r < 4; ++r)
          enc_out[(((size_t)(grp * 16 + quad * 4 + r) * S_ + step)) * H_ + kcol] = hb[r];
      }
      {
        unsigned short* hxs = hx + ((size_t)((t & 1) * 32 + grp * 2 + half)) * 2048;
        u64_ pack = (u64_)pkA | ((u64_)pkB << 32);
        __hip_atomic_store((u64_*)(hxs + kloc * 16 + quad * 4), pack,
                           __ATOMIC_RELAXED, __HIP_MEMORY_SCOPE_AGENT);
      }
      __syncthreads();  // (a) hbuf/xin reads done; hx stores drained to L3 (vmcnt0)
      if (phase == 0 && tid < 32) xin[tid >> 1][tid & 1] = xpre;
      if (tid == 0) {
        __hip_atomic_store(myflag, (unsigned int)(t + 1), __ATOMIC_RELAXED,
                           __HIP_MEMORY_SCOPE_AGENT);
        while (__hip_atomic_load(pflag, __ATOMIC_RELAXED, __HIP_MEMORY_SCOPE_AGENT) <
               (unsigned int)(t + 1)) {
          __builtin_amdgcn_s_sleep(1);
        }
      }
      __syncthreads();  // (b)
      // ---- update LDS h: own half from regs, peer half from hx ----
#pragma unroll
      for (int r = 0; r < 4; ++r) hbuf[(quad * 4 + r) * HROW + kcol] = hb[r];
      {
        const unsigned short* ph = hx + ((size_t)((t & 1) * 32 + grp * 2 + (1 - half))) * 2048;
        u64_ pv = __hip_atomic_load((const u64_*)(ph + tid * 4), __ATOMIC_RELAXED,
                                    __HIP_MEMORY_SCOPE_AGENT);
        int kp = tid >> 2, r0 = (tid & 3) * 4;
        unsigned short* dst = hbuf + (1 - half) * 128 + kp;
        dst[(size_t)(r0 + 0) * HROW] = (unsigned short)(pv);
        dst[(size_t)(r0 + 1) * HROW] = (unsigned short)(pv >> 16);
        dst[(size_t)(r0 + 2) * HROW] = (unsigned short)(pv >> 32);
        dst[(size_t)(r0 + 3) * HROW] = (unsigned short)(pv >> 48);
      }
      __syncthreads();  // (c) h ready for next step
    }
  }
  // final h (fp32) for the attention query
#pragma unroll
  for (int r = 0; r < 4; ++r)
    hfin[(grp * 16 + quad * 4 + r) * H_ + kcol] = hreg[r];
}

// ---------------- K1b: q = h @ Wq^T + bq (fp32) ----------------
__global__ void k1b_q(const float* __restrict__ hfin, const float* __restrict__ Wq,
                      const float* __restrict__ bq, float* __restrict__ qbuf) {
  __shared__ float hl[H_];
  int b = blockIdx.x, j = threadIdx.x;
  hl[j] = hfin[b * H_ + j];
  __syncthreads();
  float s = bq[j];
  const float* w = Wq + j * H_;
  for (int k = 0; k < H_; ++k) s += hl[k] * w[k];
  qbuf[b * H_ + j] = s;
}

// ---------------- K2: u = tanh(enc_out@Wref^T + bref + q) @ V (fused) ----------
__launch_bounds__(512)
__global__ void k2_att(const unsigned short* __restrict__ enc_out,
                       const unsigned short* __restrict__ Wrefb,
                       const float* __restrict__ qbuf, const float* __restrict__ bref,
                       const float* __restrict__ V, float* __restrict__ ubuf) {
  __shared__ unsigned short Bs[128 * HROW];
  __shared__ float qs[128], Vs[128];
  int tid = threadIdx.x;
  int wave = tid >> 6, lane = tid & 63, quad = lane >> 4, l16 = lane & 15;
  int rowblk = blockIdx.x >> 1, nb = blockIdx.x & 1;
  int b = rowblk >> 2;
  {  // stage Wref block [nb*128 .. +128) x 256 into LDS
    int nl = tid >> 2, seg = tid & 3;
    const unsigned short* src = Wrefb + (nb * 128 + nl) * H_ + seg * 64;
    unsigned short* dst = Bs + nl * HROW + seg * 64;
#pragma unroll
    for (int i = 0; i < 8; ++i) *(u16x8*)(dst + i * 8) = *(const u16x8*)(src + i * 8);
  }
  if (tid < 128) {
    int j = nb * 128 + tid;
    qs[tid] = qbuf[b * H_ + j] + bref[j];
    Vs[tid] = V[j];
  }
  __syncthreads();
  int rw = rowblk * 128 + wave * 16 + l16;  // global (b,s) row
  const f32x4 z4 = {0.f, 0.f, 0.f, 0.f};
  f32x4 acc[8];
#pragma unroll
  for (int kt = 0; kt < 8; ++kt) {
    bf16x8 af = *(const bf16x8*)(enc_out + (size_t)rw * H_ + kt * 32 + quad * 8);
#pragma unroll
    for (int nt = 0; nt < 8; ++nt) {
      bf16x8 bfr = *(const bf16x8*)(Bs + (nt * 16 + l16) * HROW + kt * 32 + quad * 8);
      acc[nt] = __builtin_amdgcn_mfma_f32_16x16x32_bf16(af, bfr, (kt == 0) ? z4 : acc[nt],
                                                        0, 0, 0);
    }
  }
  float part[4] = {0.f, 0.f, 0.f, 0.f};
#pragma unroll
  for (int nt = 0; nt < 8; ++nt) {
    float qv = qs[nt * 16 + l16], vv = Vs[nt * 16 + l16];
#pragma unroll
    for (int r = 0; r < 4; ++r) part[r] += tanh_(acc[nt][r] + qv) * vv;
  }
#pragma unroll
  for (int m = 1; m < 16; m <<= 1) {
#pragma unroll
    for (int r = 0; r < 4; ++r) part[r] += __shfl_xor(part[r], m, 64);
  }
  if (l16 == 0) {
    int s0 = (rowblk & 3) * 128 + wave * 16 + quad * 4;
#pragma unroll
    for (int r = 0; r < 4; ++r) atomicAdd(&ubuf[b * S_ + s0 + r], part[r]);
  }
}

// ---------------- K3: softmax + glimpse + decoder head ----------------
__global__ void k3_head(const float* __restrict__ ubuf,
                        const unsigned short* __restrict__ enc_out,
                        const float* __restrict__ Wd1, const float* __restrict__ Wd2,
                        float* __restrict__ out) {
  __shared__ float sm[512];
  __shared__ float red[256];
  __shared__ float gl[256];
  int b = blockIdx.x, tid = threadIdx.x;
  float u0 = ubuf[b * S_ + tid], u1 = ubuf[b * S_ + 256 + tid];
  red[tid] = fmaxf(u0, u1);
  __syncthreads();
  for (int s = 128; s > 0; s >>= 1) {
    if (tid < s) red[tid] = fmaxf(red[tid], red[tid + s]);
    __syncthreads();
  }
  float mx = red[0];
  __syncthreads();
  float e0 = __expf(u0 - mx), e1 = __expf(u1 - mx);
  red[tid] = e0 + e1;
  __syncthreads();
  for (int s = 128; s > 0; s >>= 1) {
    if (tid < s) red[tid] += red[tid + s];
    __syncthreads();
  }
  float inv = 1.f / red[0];
  sm[tid] = e0 * inv;
  sm[256 + tid] = e1 * inv;
  __syncthreads();
  float g = 0.f;
  const unsigned short* eo = enc_out + (size_t)b * S_ * H_ + tid;
  for (int s = 0; s < S_; ++s) g += sm[s] * bf2f(eo[(size_t)s * H_]);
  gl[tid] = g;
  __syncthreads();
  float y = 0.f;
  const float* w = Wd1 + tid * H_;
  for (int j = 0; j < H_; ++j) y += w[j] * gl[j];
  y = fmaxf(y, 0.f) * Wd2[tid];
  red[tid] = y;
  __syncthreads();
  for (int s = 128; s > 0; s >>= 1) {
    if (tid < s) red[tid] += red[tid + s];
    __syncthreads();
  }
  if (tid == 0) out[b] = red[0];
}

extern "C" void kernel_launch(void* const* d_in, const int* in_sizes, int n_in,
                              void* d_out, int out_size, void* d_ws, size_t ws_size,
                              hipStream_t stream) {
  (void)in_sizes; (void)n_in; (void)out_size; (void)ws_size;
  const float* inp    = (const float*)d_in[0];
  const float* W_emb  = (const float*)d_in[1];
  const float* dec_in = (const float*)d_in[2];
  const float* eWih   = (const float*)d_in[3];
  const float* eWhh   = (const float*)d_in[4];
  const float* ebih   = (const float*)d_in[5];
  const float* ebhh   = (const float*)d_in[6];
  const float* pWih   = (const float*)d_in[7];
  const float* pWhh   = (const float*)d_in[8];
  const float* pbih   = (const float*)d_in[9];
  const float* pbhh   = (const float*)d_in[10];
  const float* Wq     = (const float*)d_in[11];
  const float* bq     = (const float*)d_in[12];
  const float* Wref   = (const float*)d_in[13];
  const float* bref   = (const float*)d_in[14];
  const float* V      = (const float*)d_in[15];
  const float* Wd1    = (const float*)d_in[16];
  const float* Wd2    = (const float*)d_in[17];
  float* out = (float*)d_out;

  char* ws = (char*)d_ws;
  unsigned short* enc_out = (unsigned short*)(ws + OFF_ENC);
  unsigned short* WhhE    = (unsigned short*)(ws + OFF_WHHE);
  unsigned short* WhhP    = (unsigned short*)(ws + OFF_WHHP);
  unsigned short* Wrefb   = (unsigned short*)(ws + OFF_WREF);
  float* Menc  = (float*)(ws + OFF_MENC);
  float* biasE = (float*)(ws + OFF_BIASE);
  float* xpv   = (float*)(ws + OFF_XPV);
  unsigned int* flags = (unsigned int*)(ws + OFF_FLAGS);
  unsigned short* hx  = (unsigned short*)(ws + OFF_HX);
  float* hfin = (float*)(ws + OFF_HFIN);
  float* qbuf = (float*)(ws + OFF_QBUF);
  float* ubuf = (float*)(ws + OFF_UBUF);

  hipLaunchKernelGGL(k0_prep, dim3(256), dim3(256), 0, stream,
                     eWih, eWhh, ebih, ebhh, pWih, pWhh, pbih, pbhh, W_emb, dec_in,
                     Wref, WhhE, WhhP, Wrefb, Menc, biasE, xpv, flags, ubuf);
  hipLaunchKernelGGL(k1_lstm, dim3(32), dim3(512), 0, stream,
                     inp, WhhE, WhhP, Menc, biasE, xpv, enc_out, hx, flags, hfin);
  hipLaunchKernelGGL(k1b_q, dim3(256), dim3(256), 0, stream, hfin, Wq, bq, qbuf);
  hipLaunchKernelGGL(k2_att, dim3(2048), dim3(512), 0, stream,
                     enc_out, Wrefb, qbuf, bref, V, ubuf);
  hipLaunchKernelGGL(k3_head, dim3(256), dim3(256), 0, stream,
                     ubuf, enc_out, Wd1, Wd2, out);
}